// Round 1
// baseline (349.686 us; speedup 1.0000x reference)
//
#include <hip/hip_runtime.h>

// RhoLoss: total = sum over pairs (l1<=l2) of w * sum_s d1[s]^T O[s] d2[s]
// S=8, I=32, N=8, K_l = I*(2l+1)*N = {256, 768, 1280, 1792}
// Pure HBM-streaming reduction over the overlap tensors (356.5 MB total).

#define NUM_S 8

// Per-pair partial sum. K1,K2 compile-time -> divisions become magic mults.
template <int K1, int K2, int W>
__device__ __forceinline__ float pair_sum(const float* __restrict__ O,
                                          const float* __restrict__ ci1,
                                          const float* __restrict__ ct1,
                                          const float* __restrict__ ci2,
                                          const float* __restrict__ ct2,
                                          int tid, int nthreads) {
    constexpr int C2    = K2 / 4;            // float4s per r1-row
    constexpr int PER_S = K1 * C2;           // float4s per structure
    constexpr int TOT4  = NUM_S * PER_S;     // float4s for this pair

    const float4* __restrict__ O4 = (const float4*)O;
    float acc = 0.0f;
    for (int idx = tid; idx < TOT4; idx += nthreads) {
        const int s   = idx / PER_S;
        const int rem = idx - s * PER_S;
        const int r1  = rem / C2;
        const int c2  = rem - r1 * C2;

        const float4 o = O4[idx];

        const float d1 = ci1[s * K1 + r1] - ct1[s * K1 + r1];

        const float4 a = ((const float4*)(ci2 + s * K2))[c2];
        const float4 b = ((const float4*)(ct2 + s * K2))[c2];

        float dot;
        dot = o.x * (a.x - b.x);
        dot = fmaf(o.y, (a.y - b.y), dot);
        dot = fmaf(o.z, (a.z - b.z), dot);
        dot = fmaf(o.w, (a.w - b.w), dot);

        acc = fmaf(d1, dot, acc);
    }
    return (float)W * acc;
}

__global__ __launch_bounds__(256) void rho_loss_kernel(
    const float* __restrict__ ci0, const float* __restrict__ ct0,
    const float* __restrict__ ci1, const float* __restrict__ ct1,
    const float* __restrict__ ci2, const float* __restrict__ ct2,
    const float* __restrict__ ci3, const float* __restrict__ ct3,
    const float* __restrict__ O00, const float* __restrict__ O01,
    const float* __restrict__ O02, const float* __restrict__ O03,
    const float* __restrict__ O11, const float* __restrict__ O12,
    const float* __restrict__ O13, const float* __restrict__ O22,
    const float* __restrict__ O23, const float* __restrict__ O33,
    float* __restrict__ out) {
    const int tid      = blockIdx.x * blockDim.x + threadIdx.x;
    const int nthreads = gridDim.x * blockDim.x;

    float acc = 0.0f;
    // K: l0=256 l1=768 l2=1280 l3=1792
    acc += pair_sum< 256,  256, 1>(O00, ci0, ct0, ci0, ct0, tid, nthreads);
    acc += pair_sum< 256,  768, 2>(O01, ci0, ct0, ci1, ct1, tid, nthreads);
    acc += pair_sum< 256, 1280, 2>(O02, ci0, ct0, ci2, ct2, tid, nthreads);
    acc += pair_sum< 256, 1792, 2>(O03, ci0, ct0, ci3, ct3, tid, nthreads);
    acc += pair_sum< 768,  768, 1>(O11, ci1, ct1, ci1, ct1, tid, nthreads);
    acc += pair_sum< 768, 1280, 2>(O12, ci1, ct1, ci2, ct2, tid, nthreads);
    acc += pair_sum< 768, 1792, 2>(O13, ci1, ct1, ci3, ct3, tid, nthreads);
    acc += pair_sum<1280, 1280, 1>(O22, ci2, ct2, ci2, ct2, tid, nthreads);
    acc += pair_sum<1280, 1792, 2>(O23, ci2, ct2, ci3, ct3, tid, nthreads);
    acc += pair_sum<1792, 1792, 1>(O33, ci3, ct3, ci3, ct3, tid, nthreads);

    // wave (64-lane) shuffle reduction
    for (int off = 32; off > 0; off >>= 1)
        acc += __shfl_down(acc, off, 64);

    __shared__ float wsum[4];
    const int lane = threadIdx.x & 63;
    const int wid  = threadIdx.x >> 6;
    if (lane == 0) wsum[wid] = acc;
    __syncthreads();
    if (threadIdx.x == 0) {
        float s = wsum[0] + wsum[1] + wsum[2] + wsum[3];
        atomicAdd(out, s);  // device-scope by default on CDNA
    }
}

extern "C" void kernel_launch(void* const* d_in, const int* in_sizes, int n_in,
                              void* d_out, int out_size, void* d_ws, size_t ws_size,
                              hipStream_t stream) {
    (void)in_sizes; (void)n_in; (void)d_ws; (void)ws_size; (void)out_size;

    const float* ci0 = (const float*)d_in[0];
    const float* ct0 = (const float*)d_in[1];
    const float* ci1 = (const float*)d_in[2];
    const float* ct1 = (const float*)d_in[3];
    const float* ci2 = (const float*)d_in[4];
    const float* ct2 = (const float*)d_in[5];
    const float* ci3 = (const float*)d_in[6];
    const float* ct3 = (const float*)d_in[7];
    const float* O00 = (const float*)d_in[8];
    const float* O01 = (const float*)d_in[9];
    const float* O02 = (const float*)d_in[10];
    const float* O03 = (const float*)d_in[11];
    const float* O11 = (const float*)d_in[12];
    const float* O12 = (const float*)d_in[13];
    const float* O13 = (const float*)d_in[14];
    const float* O22 = (const float*)d_in[15];
    const float* O23 = (const float*)d_in[16];
    const float* O33 = (const float*)d_in[17];

    // d_out is poisoned to 0xAA before every timed launch; zero it first.
    // hipMemsetAsync is graph-capturable (becomes a memset node).
    hipMemsetAsync(d_out, 0, sizeof(float), stream);

    const int threads = 256;
    const int blocks  = 2048;  // 8 blocks/CU on 256 CUs -> full occupancy
    rho_loss_kernel<<<blocks, threads, 0, stream>>>(
        ci0, ct0, ci1, ct1, ci2, ct2, ci3, ct3,
        O00, O01, O02, O03, O11, O12, O13, O22, O23, O33,
        (float*)d_out);
}

// Round 2
// 344.514 us; speedup vs baseline: 1.0150x; 1.0150x over previous
//
#include <hip/hip_runtime.h>

// RhoLoss: total = sum over pairs (l1<=l2) of w * sum_s d1[s]^T O[s] d2[s]
// S=8, I=32, N=8, K_l = I*(2l+1)*N = {256, 768, 1280, 1792}
// O traffic = 356.5 MB read once -> HBM/L3-streaming bound.
//
// R1 design: one WAVE owns one (s,r1) row of a pair's O block (row = K2
// floats = C2q float4s, contiguous). All row loads issued back-to-back
// (up to 7 KB in flight per wave). Deltas d = c_in - c_tgt precomputed
// into a 128 KB static device buffer so the inner loop is only:
//   ROUNDS x (O float4 + d2 float4) + 1 wave-uniform scalar d1.

#define NUM_S 8

// d layout in g_d: l0 @0 (2048), l1 @2048 (6144), l2 @8192 (10240), l3 @18432 (14336)
__device__ float g_d[32768];

__global__ __launch_bounds__(256) void compute_d_kernel(
    const float* __restrict__ ci0, const float* __restrict__ ct0,
    const float* __restrict__ ci1, const float* __restrict__ ct1,
    const float* __restrict__ ci2, const float* __restrict__ ct2,
    const float* __restrict__ ci3, const float* __restrict__ ct3) {
    const int t = blockIdx.x * 256 + threadIdx.x;  // 0..32767
    float v;
    if (t < 2048)       v = ci0[t]         - ct0[t];
    else if (t < 8192)  v = ci1[t - 2048]  - ct1[t - 2048];
    else if (t < 18432) v = ci2[t - 8192]  - ct2[t - 8192];
    else                v = ci3[t - 18432] - ct3[t - 18432];
    g_d[t] = v;
}

// NW = total waves in grid (power of two, hard-coded with the launch config)
#define NWAVES 8192

template <int K1, int K2, int W, int ROT>
__device__ __forceinline__ float pair_sum_rows(const float4* __restrict__ O4,
                                               const float* __restrict__ d1,
                                               const float* __restrict__ d2,
                                               int wid, int lane) {
    constexpr int C2q    = K2 / 4;     // float4s per row = 64*(2*l2+1)
    constexpr int ROUNDS = C2q / 64;   // wave-wide loads per row (1,3,5,7)
    constexpr int NROWS  = NUM_S * K1; // tasks for this pair

    float ax = 0.f, ay = 0.f, az = 0.f, aw = 0.f;
    for (int t = (wid + ROT) & (NWAVES - 1); t < NROWS; t += NWAVES) {
        const int s = t / K1;  // compile-time K1 -> magic multiply
        const float4* __restrict__ o = O4 + (size_t)t * C2q + lane;
        const float4* __restrict__ v = (const float4*)(d2 + s * K2) + lane;

        float4 ov[ROUNDS], vv[ROUNDS];
#pragma unroll
        for (int j = 0; j < ROUNDS; ++j) ov[j] = o[j * 64];
#pragma unroll
        for (int j = 0; j < ROUNDS; ++j) vv[j] = v[j * 64];

        const float dd = d1[t];  // wave-uniform (same t for all lanes)

        float dx = 0.f, dy = 0.f, dz = 0.f, dw = 0.f;
#pragma unroll
        for (int j = 0; j < ROUNDS; ++j) {
            dx = fmaf(ov[j].x, vv[j].x, dx);
            dy = fmaf(ov[j].y, vv[j].y, dy);
            dz = fmaf(ov[j].z, vv[j].z, dz);
            dw = fmaf(ov[j].w, vv[j].w, dw);
        }
        ax = fmaf(dd, dx, ax);
        ay = fmaf(dd, dy, ay);
        az = fmaf(dd, dz, az);
        aw = fmaf(dd, dw, aw);
    }
    return (float)W * ((ax + ay) + (az + aw));
}

__global__ __launch_bounds__(256) void rho_loss_kernel(
    const float* __restrict__ O00, const float* __restrict__ O01,
    const float* __restrict__ O02, const float* __restrict__ O03,
    const float* __restrict__ O11, const float* __restrict__ O12,
    const float* __restrict__ O13, const float* __restrict__ O22,
    const float* __restrict__ O23, const float* __restrict__ O33,
    float* __restrict__ out) {
    const int lane = threadIdx.x & 63;
    const int wid  = blockIdx.x * 4 + (threadIdx.x >> 6);  // global wave id

    const float* D0 = g_d;
    const float* D1 = g_d + 2048;
    const float* D2 = g_d + 8192;
    const float* D3 = g_d + 18432;

    float acc = 0.f;
    // K: l0=256 l1=768 l2=1280 l3=1792. Rotations spread per-pair tail
    // tasks across different wave ranges for load balance.
    acc += pair_sum_rows< 256,  256, 1,    0>((const float4*)O00, D0, D0, wid, lane);
    acc += pair_sum_rows< 256,  768, 2,  819>((const float4*)O01, D0, D1, wid, lane);
    acc += pair_sum_rows< 256, 1280, 2, 1638>((const float4*)O02, D0, D2, wid, lane);
    acc += pair_sum_rows< 256, 1792, 2, 2457>((const float4*)O03, D0, D3, wid, lane);
    acc += pair_sum_rows< 768,  768, 1, 3276>((const float4*)O11, D1, D1, wid, lane);
    acc += pair_sum_rows< 768, 1280, 2, 4095>((const float4*)O12, D1, D2, wid, lane);
    acc += pair_sum_rows< 768, 1792, 2, 4914>((const float4*)O13, D1, D3, wid, lane);
    acc += pair_sum_rows<1280, 1280, 1, 5733>((const float4*)O22, D2, D2, wid, lane);
    acc += pair_sum_rows<1280, 1792, 2, 6552>((const float4*)O23, D2, D3, wid, lane);
    acc += pair_sum_rows<1792, 1792, 1, 7371>((const float4*)O33, D3, D3, wid, lane);

    // wave (64-lane) shuffle reduction
    for (int off = 32; off > 0; off >>= 1)
        acc += __shfl_down(acc, off, 64);

    __shared__ float wsum[4];
    const int lwid = threadIdx.x >> 6;
    if (lane == 0) wsum[lwid] = acc;
    __syncthreads();
    if (threadIdx.x == 0) {
        float s = wsum[0] + wsum[1] + wsum[2] + wsum[3];
        atomicAdd(out, s);
    }
}

extern "C" void kernel_launch(void* const* d_in, const int* in_sizes, int n_in,
                              void* d_out, int out_size, void* d_ws, size_t ws_size,
                              hipStream_t stream) {
    (void)in_sizes; (void)n_in; (void)d_ws; (void)ws_size; (void)out_size;

    const float* ci0 = (const float*)d_in[0];
    const float* ct0 = (const float*)d_in[1];
    const float* ci1 = (const float*)d_in[2];
    const float* ct1 = (const float*)d_in[3];
    const float* ci2 = (const float*)d_in[4];
    const float* ct2 = (const float*)d_in[5];
    const float* ci3 = (const float*)d_in[6];
    const float* ct3 = (const float*)d_in[7];
    const float* O00 = (const float*)d_in[8];
    const float* O01 = (const float*)d_in[9];
    const float* O02 = (const float*)d_in[10];
    const float* O03 = (const float*)d_in[11];
    const float* O11 = (const float*)d_in[12];
    const float* O12 = (const float*)d_in[13];
    const float* O13 = (const float*)d_in[14];
    const float* O22 = (const float*)d_in[15];
    const float* O23 = (const float*)d_in[16];
    const float* O33 = (const float*)d_in[17];

    // d_out poisoned to 0xAA each call -> zero it (memset node, capture-safe)
    hipMemsetAsync(d_out, 0, sizeof(float), stream);

    // Stage deltas (32768 floats) into the static device buffer.
    compute_d_kernel<<<128, 256, 0, stream>>>(ci0, ct0, ci1, ct1,
                                              ci2, ct2, ci3, ct3);

    // 2048 blocks * 4 waves = 8192 waves (NWAVES); 8 blocks/CU.
    rho_loss_kernel<<<2048, 256, 0, stream>>>(
        O00, O01, O02, O03, O11, O12, O13, O22, O23, O33, (float*)d_out);
}

// Round 3
// 321.367 us; speedup vs baseline: 1.0881x; 1.0720x over previous
//
#include <hip/hip_runtime.h>

// RhoLoss: total = sum over pairs (l1<=l2) of w * sum_s d1[s]^T O[s] d2[s]
// S=8, I=32, N=8, K_l = I*(2l+1)*N = {256, 768, 1280, 1792}
// O traffic = 356.5 MB read once.
//
// R2: (a) O is read with non-temporal loads (nt: no-allocate) so our
// streaming misses don't evict the harness-restored dirty lines from
// L2/LLC (kills the hidden writeback traffic that capped R0/R1 at
// ~2.9 TB/s effective). (b) Static byte-balanced partition: each wave
// owns ONE pair and a contiguous row range (~43.5 KB sequential).

#define NUM_S 8

typedef float vfloat4 __attribute__((ext_vector_type(4)));

// d layout in g_d: l0 @0 (2048), l1 @2048 (6144), l2 @8192 (10240), l3 @18432 (14336)
__device__ float g_d[32768];

__global__ __launch_bounds__(256) void compute_d_kernel(
    const float* __restrict__ ci0, const float* __restrict__ ct0,
    const float* __restrict__ ci1, const float* __restrict__ ct1,
    const float* __restrict__ ci2, const float* __restrict__ ct2,
    const float* __restrict__ ci3, const float* __restrict__ ct3) {
    const int t = blockIdx.x * 256 + threadIdx.x;  // 0..32767
    float v;
    if (t < 2048)       v = ci0[t]         - ct0[t];
    else if (t < 8192)  v = ci1[t - 2048]  - ct1[t - 2048];
    else if (t < 18432) v = ci2[t - 8192]  - ct2[t - 8192];
    else                v = ci3[t - 18432] - ct3[t - 18432];
    g_d[t] = v;
}

// One pair, one wave: contiguous row range [lw*NROWS/NWP, (lw+1)*NROWS/NWP).
// K1,K2,NWP compile-time -> all div/mod become magic multiplies.
template <int K1, int K2, int W, int NWP>
__device__ __forceinline__ float pair_rows(const float* __restrict__ O,
                                           const float* __restrict__ d1,
                                           const float* __restrict__ d2,
                                           int lw, int lane) {
    constexpr int C2q    = K2 / 4;     // float4s per row
    constexpr int ROUNDS = C2q / 64;   // wave-wide float4 loads per row (1,3,5,7)
    constexpr int NROWS  = NUM_S * K1;

    const int r_beg = (int)(((long long)lw * NROWS) / NWP);
    const int r_end = (int)(((long long)(lw + 1) * NROWS) / NWP);

    const vfloat4* __restrict__ O4 = (const vfloat4*)O;

    float ax = 0.f, ay = 0.f, az = 0.f, aw = 0.f;
    for (int t = r_beg; t < r_end; ++t) {
        const int s = t / K1;
        const vfloat4* __restrict__ o = O4 + (size_t)t * C2q + lane;
        const vfloat4* __restrict__ v = (const vfloat4*)(d2 + s * K2) + lane;

        vfloat4 ov[ROUNDS], vv[ROUNDS];
#pragma unroll
        for (int j = 0; j < ROUNDS; ++j)
            ov[j] = __builtin_nontemporal_load(o + j * 64);  // nt: no-allocate
#pragma unroll
        for (int j = 0; j < ROUNDS; ++j) vv[j] = v[j * 64];

        const float dd = d1[t];  // wave-uniform

        float dx = 0.f, dy = 0.f, dz = 0.f, dw = 0.f;
#pragma unroll
        for (int j = 0; j < ROUNDS; ++j) {
            dx = fmaf(ov[j].x, vv[j].x, dx);
            dy = fmaf(ov[j].y, vv[j].y, dy);
            dz = fmaf(ov[j].z, vv[j].z, dz);
            dw = fmaf(ov[j].w, vv[j].w, dw);
        }
        ax = fmaf(dd, dx, ax);
        ay = fmaf(dd, dy, ay);
        az = fmaf(dd, dz, az);
        aw = fmaf(dd, dw, aw);
    }
    return (float)W * ((ax + ay) + (az + aw));
}

// Wave-range partition over 8192 waves, proportional to per-pair bytes
// (each wave ~43.5 KB): see table in kernel.
__global__ __launch_bounds__(256) void rho_loss_kernel(
    const float* __restrict__ O00, const float* __restrict__ O01,
    const float* __restrict__ O02, const float* __restrict__ O03,
    const float* __restrict__ O11, const float* __restrict__ O12,
    const float* __restrict__ O13, const float* __restrict__ O22,
    const float* __restrict__ O23, const float* __restrict__ O33,
    float* __restrict__ out) {
    const int lane = threadIdx.x & 63;
    const int wid  = blockIdx.x * 4 + (threadIdx.x >> 6);  // 0..8191

    const float* D0 = g_d;
    const float* D1 = g_d + 2048;
    const float* D2 = g_d + 8192;
    const float* D3 = g_d + 18432;

    float acc;
    // ranges: p00 [0,47) p01 [47,192) p02 [192,433) p03 [433,770)
    //         p11 [770,1204) p12 [1204,1927) p13 [1927,2939)
    //         p22 [2939,4144) p23 [4144,5831) p33 [5831,8192)
    if      (wid <   47) acc = pair_rows< 256,  256, 1,   47>(O00, D0, D0, wid,        lane);
    else if (wid <  192) acc = pair_rows< 256,  768, 2,  145>(O01, D0, D1, wid -   47, lane);
    else if (wid <  433) acc = pair_rows< 256, 1280, 2,  241>(O02, D0, D2, wid -  192, lane);
    else if (wid <  770) acc = pair_rows< 256, 1792, 2,  337>(O03, D0, D3, wid -  433, lane);
    else if (wid < 1204) acc = pair_rows< 768,  768, 1,  434>(O11, D1, D1, wid -  770, lane);
    else if (wid < 1927) acc = pair_rows< 768, 1280, 2,  723>(O12, D1, D2, wid - 1204, lane);
    else if (wid < 2939) acc = pair_rows< 768, 1792, 2, 1012>(O13, D1, D3, wid - 1927, lane);
    else if (wid < 4144) acc = pair_rows<1280, 1280, 1, 1205>(O22, D2, D2, wid - 2939, lane);
    else if (wid < 5831) acc = pair_rows<1280, 1792, 2, 1687>(O23, D2, D3, wid - 4144, lane);
    else                 acc = pair_rows<1792, 1792, 1, 2361>(O33, D3, D3, wid - 5831, lane);

    // wave (64-lane) shuffle reduction
    for (int off = 32; off > 0; off >>= 1)
        acc += __shfl_down(acc, off, 64);

    __shared__ float wsum[4];
    const int lwid = threadIdx.x >> 6;
    if (lane == 0) wsum[lwid] = acc;
    __syncthreads();
    if (threadIdx.x == 0) {
        float s = wsum[0] + wsum[1] + wsum[2] + wsum[3];
        atomicAdd(out, s);
    }
}

extern "C" void kernel_launch(void* const* d_in, const int* in_sizes, int n_in,
                              void* d_out, int out_size, void* d_ws, size_t ws_size,
                              hipStream_t stream) {
    (void)in_sizes; (void)n_in; (void)d_ws; (void)ws_size; (void)out_size;

    const float* ci0 = (const float*)d_in[0];
    const float* ct0 = (const float*)d_in[1];
    const float* ci1 = (const float*)d_in[2];
    const float* ct1 = (const float*)d_in[3];
    const float* ci2 = (const float*)d_in[4];
    const float* ct2 = (const float*)d_in[5];
    const float* ci3 = (const float*)d_in[6];
    const float* ct3 = (const float*)d_in[7];
    const float* O00 = (const float*)d_in[8];
    const float* O01 = (const float*)d_in[9];
    const float* O02 = (const float*)d_in[10];
    const float* O03 = (const float*)d_in[11];
    const float* O11 = (const float*)d_in[12];
    const float* O12 = (const float*)d_in[13];
    const float* O13 = (const float*)d_in[14];
    const float* O22 = (const float*)d_in[15];
    const float* O23 = (const float*)d_in[16];
    const float* O33 = (const float*)d_in[17];

    // d_out poisoned to 0xAA each call -> zero it (memset node, capture-safe)
    hipMemsetAsync(d_out, 0, sizeof(float), stream);

    // Stage deltas (32768 floats) into the static device buffer.
    compute_d_kernel<<<128, 256, 0, stream>>>(ci0, ct0, ci1, ct1,
                                              ci2, ct2, ci3, ct3);

    // 2048 blocks * 4 waves = 8192 waves; 8 blocks/CU.
    rho_loss_kernel<<<2048, 256, 0, stream>>>(
        O00, O01, O02, O03, O11, O12, O13, O22, O23, O33, (float*)d_out);
}